// Round 3
// baseline (195.934 us; speedup 1.0000x reference)
//
#include <hip/hip_runtime.h>
#include <hip/hip_bf16.h>
#include <math.h>

// Problem constants (all fp32 on the wire)
#define B_   4
#define T_   2048
#define DM   1024      // d_model
#define DH   256       // d_hidden
#define M_   (B_*T_)   // 8192 rows

typedef __bf16 bf16;
typedef __attribute__((ext_vector_type(8))) __bf16 bf16x8;
typedef __attribute__((ext_vector_type(4))) float  f32x4;

__device__ inline float sigmoidf_(float x) { return 1.0f / (1.0f + __expf(-x)); }

// T2-style LDS XOR swizzle: rows are 64 bf16 = 8 chunks of 16B.
// chunk' = chunk ^ (row & 7). Involution; same formula on write & read.
__device__ inline int swz8(int r, int c) { return (((c >> 3) ^ (r & 7)) << 3); }

// global -> LDS direct DMA, 16 B per lane. LDS dest is the WAVE base
// (HW adds lane*16). Swizzled LDS content achieved by pre-swizzling the
// per-lane global source (rule #21: linear dest + inverse-swz source).
__device__ inline void gload16(const void* g, void* l) {
    __builtin_amdgcn_global_load_lds(
        (const __attribute__((address_space(1))) void*)g,
        (__attribute__((address_space(3))) void*)l, 16, 0, 0);
}

// ---- fused: transpose+convert 4 weights, and zero numb/denb ----------------
__global__ void transpose_cvt_all(const float* __restrict__ Wq, const float* __restrict__ Wk,
                                  const float* __restrict__ Wv, const float* __restrict__ Wo,
                                  bf16* __restrict__ Wq_t, bf16* __restrict__ Wk_t,
                                  bf16* __restrict__ Wv_t, bf16* __restrict__ Wo_t,
                                  float* __restrict__ nd)
{
    const int bid = blockIdx.x;
    if (bid >= 1024) {                      // zero numb+denb (contiguous 2048 f32)
        nd[(bid - 1024) * 256 + threadIdx.x] = 0.f;
        return;
    }
    __shared__ float tile[32][33];
    const int w = bid >> 8, t = bid & 255;
    const float* in; bf16* out; int R, C, sh;
    if      (w == 0) { in = Wq; out = Wq_t; R = DM; C = DH; sh = 3; }
    else if (w == 1) { in = Wk; out = Wk_t; R = DM; C = DH; sh = 3; }
    else if (w == 2) { in = Wv; out = Wv_t; R = DM; C = DH; sh = 3; }
    else             { in = Wo; out = Wo_t; R = DH; C = DM; sh = 5; }
    const int r0 = (t >> sh) * 32, c0 = (t & ((1 << sh) - 1)) * 32;
    const int tx = threadIdx.x & 31, ty = threadIdx.x >> 5;
    #pragma unroll
    for (int i = ty; i < 32; i += 8)
        tile[i][tx] = in[(long)(r0 + i) * C + c0 + tx];
    __syncthreads();
    #pragma unroll
    for (int i = ty; i < 32; i += 8)
        out[(long)(c0 + i) * R + r0 + tx] = (bf16)tile[tx][i];
}

// ---- projections: C_z = A_z @ W_z -> bf16 [M_][DH] in ws -------------------
// Tile 64x128, BK=64, 512 thr (8 waves = 2m x 4n). Round-1 schedule
// (stage-early, dbuf, 1 barrier/slab). B staged via global_load_lds(16B)
// with pre-swizzled source; A reg-staged (fp32->bf16 cvt) with a pair-loop
// and NAMED ring slots (all register indices static even without unroll).
__global__ __launch_bounds__(512, 6)
void gemm_proj(const float* __restrict__ qin, const float* __restrict__ kin,
               const float* __restrict__ vin,
               const bf16* __restrict__ Wq_t, const bf16* __restrict__ Wk_t,
               const bf16* __restrict__ Wv_t,
               bf16* __restrict__ Yb, bf16* __restrict__ Kb, bf16* __restrict__ Vb)
{
    __shared__ __align__(16) bf16 As[2][64][64];
    __shared__ __align__(16) bf16 Bs[2][128][64];

    const int z = blockIdx.z;
    const float* A  = (z == 0) ? qin  : (z == 1) ? kin  : vin;
    const bf16*  Wt = (z == 0) ? Wq_t : (z == 1) ? Wk_t : Wv_t;
    bf16*        C  = (z == 0) ? Yb   : (z == 1) ? Kb   : Vb;

    // XCD-aware tile swizzle: contiguous chunk per XCD (256 % 8 == 0).
    const int bid  = blockIdx.x;                  // 0..255
    const int tile = (bid & 7) * 32 + (bid >> 3);
    const int m0 = (tile >> 1) * 64;
    const int n0 = (tile & 1) * 128;

    const int tid = threadIdx.x, lane = tid & 63, wave = tid >> 6;
    const int wr = wave >> 2, wc = wave & 3;   // wave: 32m x 32n
    const int q4 = lane >> 4, l16 = lane & 15;
    const int lr = lane >> 3, lc = lane & 7;

    f32x4 acc[2][2] = {};
    const int ar = tid >> 3, ac8 = (tid & 7) * 8;    // A: 64r x 64 fp32

    const float* aBase = &A[(long)(m0 + ar) * DM + ac8];

    // B DMA sources: wave w covers rows 8w..8w+7 and 64+8w..64+8w+7.
    // Source chunk pre-swizzled so LDS[r][c] holds G[r][c^(r&7)].
    const int br0 = wave * 8 + lr, br1 = 64 + wave * 8 + lr;
    const bf16* bSrc0 = &Wt[(long)(n0 + br0) * DM + ((lc ^ (br0 & 7)) * 8)];
    const bf16* bSrc1 = &Wt[(long)(n0 + br1) * DM + ((lc ^ (br1 & 7)) * 8)];

    // A register ring: two NAMED slots (slot A = even slabs, slot B = odd).
    f32x4 a0A = *(const f32x4*)(aBase);          // slab 0
    f32x4 a1A = *(const f32x4*)(aBase + 4);
    f32x4 a0B = *(const f32x4*)(aBase + 64);     // slab 1
    f32x4 a1B = *(const f32x4*)(aBase + 68);

    {   // stage A slab 0 -> As[0]; DMA B slab 0 -> Bs[0]
        gload16(bSrc0, &Bs[0][wave * 8][0]);
        gload16(bSrc1, &Bs[0][64 + wave * 8][0]);
        bf16x8 o;
        #pragma unroll
        for (int e = 0; e < 4; ++e) { o[e] = (bf16)a0A[e]; o[4 + e] = (bf16)a1A[e]; }
        *(bf16x8*)&As[0][ar][swz8(ar, ac8)] = o;
    }
    __syncthreads();

    #define MFMA_SLAB(BUF)                                                              \
        _Pragma("unroll")                                                               \
        for (int kk = 0; kk < 64; kk += 32) {                                           \
            const int ra = wr * 32 + l16, rb = wc * 32 + l16;                           \
            bf16x8 a0 = *(const bf16x8*)&As[BUF][ra     ][swz8(ra,      kk + q4 * 8)];  \
            bf16x8 a1 = *(const bf16x8*)&As[BUF][ra + 16][swz8(ra + 16, kk + q4 * 8)];  \
            bf16x8 b0 = *(const bf16x8*)&Bs[BUF][rb     ][swz8(rb,      kk + q4 * 8)];  \
            bf16x8 b1 = *(const bf16x8*)&Bs[BUF][rb + 16][swz8(rb + 16, kk + q4 * 8)];  \
            acc[0][0] = __builtin_amdgcn_mfma_f32_16x16x32_bf16(a0, b0, acc[0][0], 0, 0, 0); \
            acc[0][1] = __builtin_amdgcn_mfma_f32_16x16x32_bf16(a0, b1, acc[0][1], 0, 0, 0); \
            acc[1][0] = __builtin_amdgcn_mfma_f32_16x16x32_bf16(a1, b0, acc[1][0], 0, 0, 0); \
            acc[1][1] = __builtin_amdgcn_mfma_f32_16x16x32_bf16(a1, b1, acc[1][1], 0, 0, 0); \
        }

    for (int p = 0; p < 8; ++p) {               // 8 pairs = 16 slabs of BK=64
        const int e = 2 * p;                    // even slab: buf0, stage from slot B
        {
            gload16(bSrc0 + (e + 1) * 64, &Bs[1][wave * 8][0]);
            gload16(bSrc1 + (e + 1) * 64, &Bs[1][64 + wave * 8][0]);
            bf16x8 o;
            #pragma unroll
            for (int ee = 0; ee < 4; ++ee) { o[ee] = (bf16)a0B[ee]; o[4 + ee] = (bf16)a1B[ee]; }
            *(bf16x8*)&As[1][ar][swz8(ar, ac8)] = o;
            if (e + 2 < 16) {                   // refill slot A <- slab e+2
                a0A = *(const f32x4*)(aBase + (e + 2) * 64);
                a1A = *(const f32x4*)(aBase + (e + 2) * 64 + 4);
            }
            MFMA_SLAB(0)
            __syncthreads();
        }
        const int o_ = e + 1;                   // odd slab: buf1, stage from slot A
        {
            if (o_ + 1 < 16) {
                gload16(bSrc0 + (o_ + 1) * 64, &Bs[0][wave * 8][0]);
                gload16(bSrc1 + (o_ + 1) * 64, &Bs[0][64 + wave * 8][0]);
                bf16x8 o;
                #pragma unroll
                for (int ee = 0; ee < 4; ++ee) { o[ee] = (bf16)a0A[ee]; o[4 + ee] = (bf16)a1A[ee]; }
                *(bf16x8*)&As[0][ar][swz8(ar, ac8)] = o;
            }
            if (o_ + 2 < 16) {                  // refill slot B <- slab o+2
                a0B = *(const f32x4*)(aBase + (o_ + 2) * 64);
                a1B = *(const f32x4*)(aBase + (o_ + 2) * 64 + 4);
            }
            MFMA_SLAB(1)
            if (o_ < 15) __syncthreads();
        }
    }
    #undef MFMA_SLAB

    // C/D layout: col = lane&15, row = (lane>>4)*4 + reg. z==0 -> sigmoid.
    #pragma unroll
    for (int i = 0; i < 2; ++i)
        #pragma unroll
        for (int j = 0; j < 2; ++j)
            #pragma unroll
            for (int r = 0; r < 4; ++r) {
                int gm = m0 + wr * 32 + i * 16 + q4 * 4 + r;
                int gn = n0 + wc * 32 + j * 16 + l16;
                float v = acc[i][j][r];
                C[(long)gm * DH + gn] = (bf16)((z == 0) ? sigmoidf_(v) : v);
            }
}

// ---- exp-weighted reduction over j ----------------------------------------
__global__ void reduce_kv(const bf16* __restrict__ Kb, const bf16* __restrict__ Vb,
                          float* __restrict__ numb, float* __restrict__ denb)
{
    __shared__ float red[2][4][B_][DH];     // [arr][wave][b][d] = 32 KB
    const int tid = threadIdx.x;
    const int g = tid & 31, jj = tid >> 5;  // 32 d-groups x 8 j
    const int d8 = g * 8;
    const int j = blockIdx.x * 8 + jj;

    bf16x8 kx[B_], vx[B_];
    #pragma unroll
    for (int b = 0; b < B_; ++b) {
        kx[b] = *(const bf16x8*)&Kb[((long)b * T_ + j) * DH + d8];
        vx[b] = *(const bf16x8*)&Vb[((long)b * T_ + j) * DH + d8];
    }
    float sn[B_][8], sd[B_][8];
    #pragma unroll
    for (int e = 0; e < 8; ++e) {
        float k0 = (float)kx[0][e], k1 = (float)kx[1][e];
        float k2 = (float)kx[2][e], k3 = (float)kx[3][e];
        float mx = fmaxf(fmaxf(k0, k1), fmaxf(k2, k3));
        float e0 = __expf(k0 - mx), e1 = __expf(k1 - mx);
        float e2 = __expf(k2 - mx), e3 = __expf(k3 - mx);
        sn[0][e] = e0 * (float)vx[0][e]; sd[0][e] = e0;
        sn[1][e] = e1 * (float)vx[1][e]; sd[1][e] = e1;
        sn[2][e] = e2 * (float)vx[2][e]; sd[2][e] = e2;
        sn[3][e] = e3 * (float)vx[3][e]; sd[3][e] = e3;
    }
    #pragma unroll
    for (int b = 0; b < B_; ++b)
        #pragma unroll
        for (int e = 0; e < 8; ++e) {
            sn[b][e] += __shfl_xor(sn[b][e], 32);
            sd[b][e] += __shfl_xor(sd[b][e], 32);
        }
    const int w = tid >> 6;
    if ((tid & 32) == 0) {
        #pragma unroll
        for (int b = 0; b < B_; ++b)
            #pragma unroll
            for (int e = 0; e < 8; ++e) {
                red[0][w][b][d8 + e] = sn[b][e];
                red[1][w][b][d8 + e] = sd[b][e];
            }
    }
    __syncthreads();
    #pragma unroll
    for (int o = tid; o < 2 * B_ * DH; o += 256) {
        const int arr = o >> 10, b = (o >> 8) & 3, d = o & 255;
        float s = red[arr][0][b][d] + red[arr][1][b][d]
                + red[arr][2][b][d] + red[arr][3][b][d];
        float* dst = (o < 1024) ? &numb[o] : &denb[o - 1024];
        atomicAdd(dst, s);
    }
}

// ---- fold rv = numb/denb into 4 batch-scaled copies of Wo_t ----------------
// Wo_b[b][n][d] = Wo_t[n][d] * rv[b][d]. 128 blocks x 256 thr, 1 (n,d8)/thread.
__global__ void scale_wo(const bf16* __restrict__ Wo_t, const float* __restrict__ numb,
                         const float* __restrict__ denb, bf16* __restrict__ Wo_b)
{
    const int t = blockIdx.x * 256 + threadIdx.x;   // 0..32767
    const int n = t >> 5, d8 = (t & 31) * 8;
    bf16x8 w = *(const bf16x8*)&Wo_t[((long)n << 8) + d8];
    #pragma unroll
    for (int b = 0; b < B_; ++b) {
        f32x4 nv0 = *(const f32x4*)&numb[b * DH + d8];
        f32x4 nv1 = *(const f32x4*)&numb[b * DH + d8 + 4];
        f32x4 dv0 = *(const f32x4*)&denb[b * DH + d8];
        f32x4 dv1 = *(const f32x4*)&denb[b * DH + d8 + 4];
        bf16x8 o;
        #pragma unroll
        for (int e = 0; e < 4; ++e) {
            o[e]     = (bf16)((float)w[e]     * (nv0[e] / dv0[e]));
            o[4 + e] = (bf16)((float)w[4 + e] * (nv1[e] / dv1[e]));
        }
        *(bf16x8*)&Wo_b[((long)b << 18) + ((long)n << 8) + d8] = o;
    }
}

// ---- output GEMM: out = Yb @ Wo_b[batch], fp32 out -------------------------
// Pure GEMM: BOTH tiles DMA-staged via global_load_lds (pre-swizzled source),
// zero staging VALU. Tile 64x128, K=256 (4 slabs), dbuf, 1 barrier/slab.
// Epilogue bounces C through LDS for dwordx4 coalesced fp32 stores.
__global__ __launch_bounds__(512, 6)
void gemm_out(const bf16* __restrict__ Yb, const bf16* __restrict__ Wo_b,
              float* __restrict__ out)
{
    __shared__ __align__(16) char smem[49152];
    auto As = reinterpret_cast<bf16 (*)[64][64]>(smem);            // 2 x 8 KB
    auto Bs = reinterpret_cast<bf16 (*)[128][64]>(smem + 16384);   // 2 x 16 KB
    auto Cb = reinterpret_cast<float (*)[132]>(smem);              // 64 x 528 B (epilogue)

    // XCD-aware tile swizzle (1024 % 8 == 0): A panels (8x n-reuse) per XCD.
    const int bid  = blockIdx.x;                   // 0..1023
    const int tile = (bid & 7) * 128 + (bid >> 3);
    const int m0 = (tile >> 3) * 64;
    const int n0 = (tile & 7) * 128;
    const int b  = m0 >> 11;                       // batch = m0/2048

    const int tid = threadIdx.x, lane = tid & 63, wave = tid >> 6;
    const int wr = wave >> 2, wc = wave & 3;
    const int q4 = lane >> 4, l16 = lane & 15;
    const int lr = lane >> 3, lc = lane & 7;

    f32x4 acc[2][2] = {};

    // DMA sources (pre-swizzled chunk per lane). Row strides: 256 bf16 = 512 B.
    const int arw = wave * 8 + lr;                           // A row (0..63)
    const int br0 = wave * 8 + lr, br1 = 64 + wave * 8 + lr; // B rows
    const bf16* aSrc  = &Yb[((long)(m0 + arw) << 8) + ((lc ^ (arw & 7)) * 8)];
    const bf16* bSrc0 = &Wo_b[((long)b << 18) + ((long)(n0 + br0) << 8) + ((lc ^ (br0 & 7)) * 8)];
    const bf16* bSrc1 = &Wo_b[((long)b << 18) + ((long)(n0 + br1) << 8) + ((lc ^ (br1 & 7)) * 8)];

    gload16(aSrc,  &As[0][wave * 8][0]);
    gload16(bSrc0, &Bs[0][wave * 8][0]);
    gload16(bSrc1, &Bs[0][64 + wave * 8][0]);
    __syncthreads();

    #pragma unroll
    for (int s = 0; s < 4; ++s) {               // 4 slabs of BK=64
        const int cs = s & 1, ns = cs ^ 1;
        if (s + 1 < 4) {
            gload16(aSrc  + (s + 1) * 64, &As[ns][wave * 8][0]);
            gload16(bSrc0 + (s + 1) * 64, &Bs[ns][wave * 8][0]);
            gload16(bSrc1 + (s + 1) * 64, &Bs[ns][64 + wave * 8][0]);
        }
        #pragma unroll
        for (int kk = 0; kk < 64; kk += 32) {
            const int ra = wr * 32 + l16, rb = wc * 32 + l16;
            bf16x8 a0 = *(const bf16x8*)&As[cs][ra     ][swz8(ra,      kk + q4 * 8)];
            bf16x8 a1 = *(const bf16x8*)&As[cs][ra + 16][swz8(ra + 16, kk + q4 * 8)];
            bf16x8 b0 = *(const bf16x8*)&Bs[cs][rb     ][swz8(rb,      kk + q4 * 8)];
            bf16x8 b1 = *(const bf16x8*)&Bs[cs][rb + 16][swz8(rb + 16, kk + q4 * 8)];
            acc[0][0] = __builtin_amdgcn_mfma_f32_16x16x32_bf16(a0, b0, acc[0][0], 0, 0, 0);
            acc[0][1] = __builtin_amdgcn_mfma_f32_16x16x32_bf16(a0, b1, acc[0][1], 0, 0, 0);
            acc[1][0] = __builtin_amdgcn_mfma_f32_16x16x32_bf16(a1, b0, acc[1][0], 0, 0, 0);
            acc[1][1] = __builtin_amdgcn_mfma_f32_16x16x32_bf16(a1, b1, acc[1][1], 0, 0, 0);
        }
        __syncthreads();                        // also fences LDS before epilogue
    }

    // Epilogue: acc -> LDS (padded stride 132) -> dwordx4 coalesced stores.
    #pragma unroll
    for (int i = 0; i < 2; ++i)
        #pragma unroll
        for (int j = 0; j < 2; ++j)
            #pragma unroll
            for (int r = 0; r < 4; ++r)
                Cb[wr * 32 + i * 16 + q4 * 4 + r][wc * 32 + j * 16 + l16] = acc[i][j][r];
    __syncthreads();
    const int orow = tid >> 3, oc = (tid & 7) * 4;           // dword col offset
    float* orp = &out[(long)(m0 + orow) * DM + n0];
    #pragma unroll
    for (int c2 = 0; c2 < 4; ++c2)
        *(f32x4*)&orp[oc + 32 * c2] = *(const f32x4*)&Cb[orow][oc + 32 * c2];
}

// ---------------- launch ----------------
extern "C" void kernel_launch(void* const* d_in, const int* in_sizes, int n_in,
                              void* d_out, int out_size, void* d_ws, size_t ws_size,
                              hipStream_t stream)
{
    const float* q  = (const float*)d_in[0];
    const float* k  = (const float*)d_in[1];
    const float* v  = (const float*)d_in[2];
    const float* Wq = (const float*)d_in[3];
    const float* Wk = (const float*)d_in[4];
    const float* Wv = (const float*)d_in[5];
    const float* Wo = (const float*)d_in[6];
    // d_in[7] = W_bias: provably unused (exp_pos_bias == ones)
    float* out = (float*)d_out;

    // Workspace: 14.02 MB (Wo_b reuses dead Kb space after reduce_kv)
    char* ws = (char*)d_ws;
    bf16* Yb    = (bf16*)ws;  ws += (size_t)M_ * DH * sizeof(bf16);   // sigmoid(Q), 4 MB
    bf16* Kb    = (bf16*)ws;  ws += (size_t)M_ * DH * sizeof(bf16);   // 4 MB
    bf16* Vb    = (bf16*)ws;  ws += (size_t)M_ * DH * sizeof(bf16);   // 4 MB
    bf16* Wq_t  = (bf16*)ws;  ws += (size_t)DM * DH * sizeof(bf16);   // 0.5 MB
    bf16* Wk_t  = (bf16*)ws;  ws += (size_t)DM * DH * sizeof(bf16);
    bf16* Wv_t  = (bf16*)ws;  ws += (size_t)DM * DH * sizeof(bf16);
    bf16* Wo_t  = (bf16*)ws;  ws += (size_t)DM * DH * sizeof(bf16);
    float* numb = (float*)ws; ws += (size_t)B_ * DH * sizeof(float);  // 4 KB
    float* denb = (float*)ws; ws += (size_t)B_ * DH * sizeof(float);  // contiguous after numb
    bf16* Wo_b  = Kb;   // 2 MB needed, 4 MB available; Kb dead after reduce_kv

    transpose_cvt_all<<<1032, 256, 0, stream>>>(Wq, Wk, Wv, Wo,
                                                Wq_t, Wk_t, Wv_t, Wo_t, numb);

    gemm_proj<<<dim3(256, 1, 3), 512, 0, stream>>>(q, k, v, Wq_t, Wk_t, Wv_t,
                                                   Yb, Kb, Vb);
    reduce_kv<<<256, 256, 0, stream>>>(Kb, Vb, numb, denb);
    scale_wo<<<128, 256, 0, stream>>>(Wo_t, numb, denb, Wo_b);
    gemm_out<<<1024, 512, 0, stream>>>(Yb, Wo_b, out);
}